// Round 1
// baseline (230.065 us; speedup 1.0000x reference)
//
#include <hip/hip_runtime.h>
#include <math.h>

#define C_NUM 64
#define CELLS 125

__global__ __launch_bounds__(256) void pooler_kernel(
    const float* __restrict__ x0, const float* __restrict__ x1,
    const float* __restrict__ x2, const float* __restrict__ x3,
    const float* __restrict__ bbox, const int* __restrict__ bids,
    float* __restrict__ out, int total)
{
    int idx = blockIdx.x * blockDim.x + threadIdx.x;
    if (idx >= total) return;

    int cell = idx % CELLS;
    int rc   = idx / CELLS;
    int ch   = rc % C_NUM;
    int r    = rc / C_NUM;

    const float b0 = bbox[r * 7 + 0];
    const float b1 = bbox[r * 7 + 1];
    const float b2 = bbox[r * 7 + 2];
    const float b3 = bbox[r * 7 + 3];
    const float b4 = bbox[r * 7 + 4];
    const float b5 = bbox[r * 7 + 5];
    const float b6 = bbox[r * 7 + 6];
    const int bid  = bids[r];

    // level selection: argmin |SCALES - sqrt(max(b3,b4))/20|, first-min wins
    float rate = sqrtf(fmaxf(b3, b4)) / 20.0f;
    const float SC[4] = {0.25f, 0.125f, 0.0625f, 0.03125f};
    int lvl = 0;
    float best = fabsf(SC[0] - rate);
    #pragma unroll
    for (int j = 1; j < 4; ++j) {
        float d = fabsf(SC[j] - rate);
        if (d < best) { best = d; lvl = j; }
    }
    const float scale = SC[lvl];

    const float* f;
    int D;
    if (lvl == 0)      { f = x0; D = 64; }
    else if (lvl == 1) { f = x1; D = 32; }
    else if (lvl == 2) { f = x2; D = 16; }
    else               { f = x3; D = 8;  }
    const size_t vox = (size_t)D * D * D;
    f += ((size_t)bid * C_NUM + ch) * vox;

    // roi7 = [b1, b0, b2, b4, b3, b5, b6*(180/pi)]; theta = roi7[6]*(pi/180)
    const float ctr0 = b1 * scale;
    const float ctr1 = b0 * scale;
    const float ctr2 = b2 * scale;
    const float sz0  = b4 * scale;
    const float sz1  = b3 * scale;
    const float sz2  = b5 * scale;
    const float theta = (b6 * (180.0f / (float)M_PI)) * ((float)M_PI / 180.0f);
    const float ct = cosf(theta);
    const float st = sinf(theta);

    const int i2 = cell % 5;
    const int i1 = (cell / 5) % 5;
    const int i0 = cell / 25;

    const float Df = (float)D;
    float acc = 0.0f;

    #pragma unroll
    for (int s0 = 0; s0 < 2; ++s0)
    #pragma unroll
    for (int s1 = 0; s1 < 2; ++s1)
    #pragma unroll
    for (int s2 = 0; s2 < 2; ++s2) {
        // axis samples: u = (bin + (s+0.5)/sr) / n, n=5, sr=2
        float u0 = ((float)i0 + ((float)s0 + 0.5f) * 0.5f) / 5.0f;
        float u1 = ((float)i1 + ((float)s1 + 0.5f) * 0.5f) / 5.0f;
        float u2 = ((float)i2 + ((float)s2 + 0.5f) * 0.5f) / 5.0f;
        float g0 = (u0 - 0.5f) * sz0;
        float g1 = (u1 - 0.5f) * sz1;
        float g2 = (u2 - 0.5f) * sz2;

        float px = ctr0 + (ct * g0 - st * g1);
        float py = ctr1 + (st * g0 + ct * g1);
        float pz = ctr2 + g2;

        bool valid = (px > -1.0f) && (px < Df) &&
                     (py > -1.0f) && (py < Df) &&
                     (pz > -1.0f) && (pz < Df);

        float q0 = fminf(fmaxf(px, 0.0f), Df - 1.0f);
        float q1 = fminf(fmaxf(py, 0.0f), Df - 1.0f);
        float q2 = fminf(fmaxf(pz, 0.0f), Df - 1.0f);

        int a0 = (int)q0, a1 = (int)q1, a2 = (int)q2;
        float f0 = q0 - (float)a0;
        float f1 = q1 - (float)a1;
        float f2 = q2 - (float)a2;
        int e0 = min(a0 + 1, D - 1);
        int e1 = min(a1 + 1, D - 1);
        int e2 = min(a2 + 1, D - 1);

        const float* p00 = f + ((size_t)a0 * D + a1) * D;
        const float* p01 = f + ((size_t)a0 * D + e1) * D;
        const float* p10 = f + ((size_t)e0 * D + a1) * D;
        const float* p11 = f + ((size_t)e0 * D + e1) * D;

        float w2a = 1.0f - f2, w2b = f2;
        float v00 = p00[a2] * w2a + p00[e2] * w2b;
        float v01 = p01[a2] * w2a + p01[e2] * w2b;
        float v10 = p10[a2] * w2a + p10[e2] * w2b;
        float v11 = p11[a2] * w2a + p11[e2] * w2b;

        float v0 = v00 * (1.0f - f1) + v01 * f1;
        float v1 = v10 * (1.0f - f1) + v11 * f1;
        float v  = v0 * (1.0f - f0) + v1 * f0;

        acc += valid ? v : 0.0f;
    }

    out[(size_t)idx] = acc * 0.125f;
}

extern "C" void kernel_launch(void* const* d_in, const int* in_sizes, int n_in,
                              void* d_out, int out_size, void* d_ws, size_t ws_size,
                              hipStream_t stream) {
    const float* x0   = (const float*)d_in[0];
    const float* x1   = (const float*)d_in[1];
    const float* x2   = (const float*)d_in[2];
    const float* x3   = (const float*)d_in[3];
    const float* bbox = (const float*)d_in[4];
    const int*   bids = (const int*)d_in[5];
    float* out = (float*)d_out;

    int total = out_size;  // R * C * 125
    int block = 256;
    int grid = (total + block - 1) / block;
    hipLaunchKernelGGL(pooler_kernel, dim3(grid), dim3(block), 0, stream,
                       x0, x1, x2, x3, bbox, bids, out, total);
}

// Round 2
// 199.284 us; speedup vs baseline: 1.1545x; 1.1545x over previous
//
#include <hip/hip_runtime.h>
#include <math.h>

#define RX 10
#define RY 10
#define RZ 5
#define REG_N (RX * RY * RZ)   // 500 voxels per channel region
#define CHB 8                  // channels per block
#define C_NUM 64
#define NP 1000                // sample points per roi (125 cells * 8 subsamples)
#define NCELL 125

// LDS: region 8*500*4=16000 + base 4000 + pack 4000 + f0/f1/f2 12000 + out 4000 = 40000 B
// -> 4 blocks/CU (160KB LDS), 16 waves/CU.
__global__ __launch_bounds__(256, 4) void pooler_kernel(
    const float* __restrict__ x0, const float* __restrict__ x1,
    const float* __restrict__ x2, const float* __restrict__ x3,
    const float* __restrict__ bbox, const int* __restrict__ bids,
    float* __restrict__ out)
{
    __shared__ float reg[CHB * REG_N];
    __shared__ int   p_base[NP];
    __shared__ int   p_pack[NP];
    __shared__ float p_f0[NP];
    __shared__ float p_f1[NP];
    __shared__ float p_f2[NP];
    __shared__ float out_lds[CHB * NCELL];

    const int blk = blockIdx.x;
    const int r   = blk >> 3;       // roi index (128)
    const int cg  = blk & 7;        // channel group (8 groups of 8)
    const int tid = threadIdx.x;

    // ---- per-roi params (wave-uniform, recomputed by all threads) ----
    const float b0 = bbox[r * 7 + 0];
    const float b1 = bbox[r * 7 + 1];
    const float b2 = bbox[r * 7 + 2];
    const float b3 = bbox[r * 7 + 3];
    const float b4 = bbox[r * 7 + 4];
    const float b5 = bbox[r * 7 + 5];
    const float b6 = bbox[r * 7 + 6];
    const int bid  = bids[r];

    // level select: argmin |SC - sqrt(max(b3,b4))/20|, first min wins
    const float rate = sqrtf(fmaxf(b3, b4)) / 20.0f;
    const float SC[4] = {0.25f, 0.125f, 0.0625f, 0.03125f};
    int lvl = 0;
    float best = fabsf(SC[0] - rate);
    #pragma unroll
    for (int j = 1; j < 4; ++j) {
        float d = fabsf(SC[j] - rate);
        if (d < best) { best = d; lvl = j; }
    }
    const float scale = SC[lvl];

    const float* f;
    int D;
    if (lvl == 0)      { f = x0; D = 64; }
    else if (lvl == 1) { f = x1; D = 32; }
    else if (lvl == 2) { f = x2; D = 16; }
    else               { f = x3; D = 8;  }

    // roi7 = [b1,b0,b2,b4,b3,b5, b6*(180/pi)]; theta = roi7[6]*(pi/180)
    const float ctr0 = b1 * scale;
    const float ctr1 = b0 * scale;
    const float ctr2 = b2 * scale;
    const float sz0  = b4 * scale;
    const float sz1  = b3 * scale;
    const float sz2  = b5 * scale;
    const float theta = (b6 * (180.0f / (float)M_PI)) * ((float)M_PI / 180.0f);
    float st, ct;
    sincosf(theta, &st, &ct);
    const float Df = (float)D;

    // conservative region bounds: samples at u in [0.05, 0.95] -> g in +-0.45*sz
    const float hx = 0.451f * (fabsf(ct) * sz0 + fabsf(st) * sz1) + 0.01f;
    const float hy = 0.451f * (fabsf(st) * sz0 + fabsf(ct) * sz1) + 0.01f;
    const float hz = 0.451f * sz2 + 0.01f;
    const int x_lo = (int)fminf(fmaxf(ctr0 - hx, 0.0f), Df - 1.0f);
    const int y_lo = (int)fminf(fmaxf(ctr1 - hy, 0.0f), Df - 1.0f);
    const int z_lo = (int)fminf(fmaxf(ctr2 - hz, 0.0f), Df - 1.0f);

    // ---- phase A: stage feature region for CHB channels into LDS ----
    const size_t vox = (size_t)D * D * D;
    const float* fbase = f + ((size_t)bid * C_NUM + (size_t)cg * CHB) * vox;
    for (int e = tid; e < CHB * REG_N; e += 256) {
        int ch  = e / REG_N;
        int rem = e - ch * REG_N;
        int rx  = rem / (RY * RZ);
        int r2  = rem - rx * (RY * RZ);
        int ry  = r2 / RZ;
        int rz  = r2 - ry * RZ;
        int gx = min(x_lo + rx, D - 1);
        int gy = min(y_lo + ry, D - 1);
        int gz = min(z_lo + rz, D - 1);
        reg[e] = fbase[(size_t)ch * vox + ((size_t)gx * D + gy) * D + gz];
    }

    // ---- phase B: per-sample-point params (shared across channels) ----
    for (int p = tid; p < NP; p += 256) {
        int cell = p >> 3, s = p & 7;
        int i0 = cell / 25, i1 = (cell / 5) % 5, i2 = cell % 5;
        int s0 = (s >> 2) & 1, s1 = (s >> 1) & 1, s2 = s & 1;
        float u0 = ((float)i0 + ((float)s0 + 0.5f) * 0.5f) / 5.0f;
        float u1 = ((float)i1 + ((float)s1 + 0.5f) * 0.5f) / 5.0f;
        float u2 = ((float)i2 + ((float)s2 + 0.5f) * 0.5f) / 5.0f;
        float g0 = (u0 - 0.5f) * sz0;
        float g1 = (u1 - 0.5f) * sz1;
        float g2 = (u2 - 0.5f) * sz2;
        float px = ctr0 + (ct * g0 - st * g1);
        float py = ctr1 + (st * g0 + ct * g1);
        float pz = ctr2 + g2;
        int valid = (px > -1.0f) && (px < Df) &&
                    (py > -1.0f) && (py < Df) &&
                    (pz > -1.0f) && (pz < Df);
        float q0 = fminf(fmaxf(px, 0.0f), Df - 1.0f);
        float q1 = fminf(fmaxf(py, 0.0f), Df - 1.0f);
        float q2 = fminf(fmaxf(pz, 0.0f), Df - 1.0f);
        int a0 = (int)q0, a1 = (int)q1, a2 = (int)q2;
        int e0 = min(a0 + 1, D - 1) - a0;   // 0 or 1
        int e1 = min(a1 + 1, D - 1) - a1;
        int e2 = min(a2 + 1, D - 1) - a2;
        p_f0[p] = q0 - (float)a0;
        p_f1[p] = q1 - (float)a1;
        p_f2[p] = q2 - (float)a2;
        p_base[p] = ((a0 - x_lo) * RY + (a1 - y_lo)) * RZ + (a2 - z_lo);
        p_pack[p] = e0 | (e1 << 1) | (e2 << 2) | (valid << 3);
    }
    __syncthreads();

    // ---- phase C: compute outputs from LDS ----
    for (int o = tid; o < CHB * NCELL; o += 256) {
        int ch   = o & (CHB - 1);
        int cell = o >> 3;
        const float* rg = &reg[ch * REG_N];
        float acc = 0.0f;
        #pragma unroll
        for (int s = 0; s < 8; ++s) {
            int p = (cell << 3) | s;
            int base = p_base[p];
            int pk   = p_pack[p];
            float f0 = p_f0[p], f1 = p_f1[p], f2 = p_f2[p];
            int d0 = (pk & 1) ? (RY * RZ) : 0;
            int d1 = (pk & 2) ? RZ : 0;
            int d2 = (pk & 4) ? 1 : 0;
            float v000 = rg[base];
            float v001 = rg[base + d2];
            float v010 = rg[base + d1];
            float v011 = rg[base + d1 + d2];
            float v100 = rg[base + d0];
            float v101 = rg[base + d0 + d2];
            float v110 = rg[base + d0 + d1];
            float v111 = rg[base + d0 + d1 + d2];
            float w2a = 1.0f - f2, w2b = f2;
            float v00 = v000 * w2a + v001 * w2b;
            float v01 = v010 * w2a + v011 * w2b;
            float v10 = v100 * w2a + v101 * w2b;
            float v11 = v110 * w2a + v111 * w2b;
            float v0 = v00 * (1.0f - f1) + v01 * f1;
            float v1 = v10 * (1.0f - f1) + v11 * f1;
            float v  = v0 * (1.0f - f0) + v1 * f0;
            acc += (pk & 8) ? v : 0.0f;
        }
        out_lds[ch * NCELL + cell] = acc * 0.125f;
    }
    __syncthreads();

    // ---- phase D: coalesced writeback (block's 1000 outputs are contiguous) ----
    float* ob = out + (size_t)r * (C_NUM * NCELL) + (size_t)cg * (CHB * NCELL);
    for (int e = tid; e < CHB * NCELL; e += 256) {
        ob[e] = out_lds[e];
    }
}

extern "C" void kernel_launch(void* const* d_in, const int* in_sizes, int n_in,
                              void* d_out, int out_size, void* d_ws, size_t ws_size,
                              hipStream_t stream) {
    const float* x0   = (const float*)d_in[0];
    const float* x1   = (const float*)d_in[1];
    const float* x2   = (const float*)d_in[2];
    const float* x3   = (const float*)d_in[3];
    const float* bbox = (const float*)d_in[4];
    const int*   bids = (const int*)d_in[5];
    float* out = (float*)d_out;

    // 128 rois * 8 channel-groups = 1024 blocks
    hipLaunchKernelGGL(pooler_kernel, dim3(1024), dim3(256), 0, stream,
                       x0, x1, x2, x3, bbox, bids, out);
}